// Round 1
// baseline (2756.828 us; speedup 1.0000x reference)
//
#include <hip/hip_runtime.h>
#include <stdint.h>

#define CAPACITY  65536
#define BATCH     2048
#define KEY_WORDS 32        // 1024 bits / 32
#define CHUNK     128       // keys staged in LDS per iteration
#define KTILE     8192      // keys per scan block
#define QB        8         // queries per block
#define QPT       4         // queries per thread (2 groups of 128 threads)

// ---------------------------------------------------------------------------
// Pack 0/1 int32 bits into u32 words. word w covers input[w*32 .. w*32+31].
// Bit order is irrelevant as long as query/keys use the same packing.
__global__ void pack_bits_kernel(const int* __restrict__ in,
                                 uint32_t* __restrict__ out, int nwords) {
    int w = blockIdx.x * blockDim.x + threadIdx.x;
    if (w >= nwords) return;
    const int4* p = reinterpret_cast<const int4*>(in) + (size_t)w * 8;
    uint32_t word = 0;
#pragma unroll
    for (int j = 0; j < 8; ++j) {
        int4 v = p[j];
        word |= (uint32_t)(v.x & 1) << (4 * j + 0);
        word |= (uint32_t)(v.y & 1) << (4 * j + 1);
        word |= (uint32_t)(v.z & 1) << (4 * j + 2);
        word |= (uint32_t)(v.w & 1) << (4 * j + 3);
    }
    out[w] = word;
}

// ---------------------------------------------------------------------------
// Scan: each block = 8 queries x 8192 keys. Threads 0..127 handle queries
// 0..3 (in registers), threads 128..255 handle queries 4..7. Keys staged in
// LDS 128 at a time, transposed [w4][key] so ds_read_b128 across lanes is
// conflict-floor. Packed best = (dist<<16)|key_idx minimized -> first-max
// argmax semantics of the reference.
__launch_bounds__(256, 3)
__global__ void scan_kernel(const uint32_t* __restrict__ qpack,
                            const uint32_t* __restrict__ kpack,
                            uint32_t* __restrict__ partials) {
    __shared__ uint4 lds[8 * CHUNK];    // [w4][key], 16 KB
    __shared__ uint32_t red[4][4];      // per-wave reduction scratch

    const int t     = threadIdx.x;
    const int ktile = blockIdx.x & 7;       // same ktile -> same XCD (L2 pin)
    const int qtile = blockIdx.x >> 3;
    const int g     = t >> 7;                // query group 0/1
    const int tk    = t & 127;               // key slot within chunk
    const int qbase = qtile * QB + g * QPT;

    const uint4* qp4 = reinterpret_cast<const uint4*>(qpack);
    const uint4* kp4 = reinterpret_cast<const uint4*>(kpack);

    // 4 queries resident in registers: 4 x 8 x uint4 = 128 VGPRs
    uint4 q[QPT][8];
#pragma unroll
    for (int i = 0; i < QPT; ++i)
#pragma unroll
        for (int j = 0; j < 8; ++j)
            q[i][j] = qp4[(size_t)(qbase + i) * 8 + j];

    uint32_t best[QPT] = {0xFFFFFFFFu, 0xFFFFFFFFu, 0xFFFFFFFFu, 0xFFFFFFFFu};

    const int k0 = ktile * KTILE;
    for (int c = 0; c < KTILE; c += CHUNK) {
        // ---- stage 128 keys (16 KB) into LDS, transposed -----------------
#pragma unroll
        for (int j = 0; j < 4; ++j) {
            int i = j * 256 + t;                       // linear uint4 index
            uint4 v = kp4[(size_t)(k0 + c) * 8 + i];   // coalesced
            lds[(i & 7) * CHUNK + (i >> 3)] = v;       // [w4][key]
        }
        __syncthreads();

        // ---- 1 key per thread vs 4 resident queries ----------------------
        uint32_t dist[QPT] = {0, 0, 0, 0};
#pragma unroll
        for (int w4 = 0; w4 < 8; ++w4) {
            uint4 kv = lds[w4 * CHUNK + tk];
#pragma unroll
            for (int i = 0; i < QPT; ++i) {
                dist[i] += __popc(kv.x ^ q[i][w4].x);
                dist[i] += __popc(kv.y ^ q[i][w4].y);
                dist[i] += __popc(kv.z ^ q[i][w4].z);
                dist[i] += __popc(kv.w ^ q[i][w4].w);
            }
        }
        uint32_t gk = (uint32_t)(k0 + c + tk);         // global key idx <= 65535
#pragma unroll
        for (int i = 0; i < QPT; ++i) {
            uint32_t packed = (dist[i] << 16) | gk;    // min => min dist, then min idx
            best[i] = min(best[i], packed);
        }
        __syncthreads();
    }

    // ---- reduce across the 128 threads of each group ----------------------
#pragma unroll
    for (int i = 0; i < QPT; ++i) {
        uint32_t b = best[i];
        for (int off = 32; off; off >>= 1)
            b = min(b, (uint32_t)__shfl_xor((int)b, off, 64));
        best[i] = b;
    }
    const int wave = t >> 6;
    if ((t & 63) == 0) {
#pragma unroll
        for (int i = 0; i < QPT; ++i) red[wave][i] = best[i];
    }
    __syncthreads();
    if (t < 8) {
        int g2 = t >> 2, i = t & 3;
        uint32_t v = min(red[g2 * 2][i], red[g2 * 2 + 1][i]);
        partials[(size_t)(qtile * QB + g2 * QPT + i) * 8 + ktile] = v;
    }
}

// ---------------------------------------------------------------------------
// Finalize: min over 8 ktile partials -> gather values row (1024 f32).
__global__ void finalize_kernel(const uint32_t* __restrict__ partials,
                                const float* __restrict__ values,
                                float* __restrict__ out) {
    const int q = blockIdx.x;
    const int t = threadIdx.x;
    uint32_t m = 0xFFFFFFFFu;
#pragma unroll
    for (int j = 0; j < 8; ++j) m = min(m, partials[q * 8 + j]);
    const int idx = (int)(m & 0xFFFFu);
    const float4* v4 = reinterpret_cast<const float4*>(values) + (size_t)idx * 256;
    float4* o4 = reinterpret_cast<float4*>(out) + (size_t)q * 256;
    o4[t] = v4[t];
}

// ---------------------------------------------------------------------------
extern "C" void kernel_launch(void* const* d_in, const int* in_sizes, int n_in,
                              void* d_out, int out_size, void* d_ws, size_t ws_size,
                              hipStream_t stream) {
    const int*   query  = (const int*)d_in[0];   // [2048, 1024] int32 0/1
    const int*   keys   = (const int*)d_in[1];   // [65536, 1024] int32 0/1
    const float* values = (const float*)d_in[2]; // [65536, 1024] f32
    float*       out    = (float*)d_out;         // [2048, 1024] f32

    char* ws = (char*)d_ws;
    uint32_t* qpack    = (uint32_t*)ws;                        // 256 KB
    uint32_t* kpack    = (uint32_t*)(ws + 262144);             // 8 MB
    uint32_t* partials = (uint32_t*)(ws + 262144 + 8388608);   // 64 KB

    pack_bits_kernel<<<BATCH * KEY_WORDS / 256, 256, 0, stream>>>(
        query, qpack, BATCH * KEY_WORDS);
    pack_bits_kernel<<<CAPACITY * KEY_WORDS / 256, 256, 0, stream>>>(
        keys, kpack, CAPACITY * KEY_WORDS);

    scan_kernel<<<(BATCH / QB) * (CAPACITY / KTILE), 256, 0, stream>>>(
        qpack, kpack, partials);

    finalize_kernel<<<BATCH, 256, 0, stream>>>(partials, values, out);
}

// Round 2
// 636.270 us; speedup vs baseline: 4.3328x; 4.3328x over previous
//
#include <hip/hip_runtime.h>
#include <stdint.h>

#define CAPACITY  65536
#define BATCH     2048
#define KEY_WORDS 32        // 1024 bits / 32
#define CHUNK     128       // keys staged in LDS per iteration
#define LSTRIDE   (CHUNK + 1)  // padded transposed stride (uint4 units)
#define KTILE     8192      // keys per scan block
#define QB        8         // queries per block
#define QPT       4         // queries per thread (2 groups of 128 threads)

// ---------------------------------------------------------------------------
// Pack 0/1 int32 bits into u32 words. word w covers input[w*32 .. w*32+31].
// Bit order is irrelevant as long as query/keys use the same packing.
__global__ void pack_bits_kernel(const int* __restrict__ in,
                                 uint32_t* __restrict__ out, int nwords) {
    int w = blockIdx.x * blockDim.x + threadIdx.x;
    if (w >= nwords) return;
    const int4* p = reinterpret_cast<const int4*>(in) + (size_t)w * 8;
    uint32_t word = 0;
#pragma unroll
    for (int j = 0; j < 8; ++j) {
        int4 v = p[j];
        word |= (uint32_t)(v.x & 1) << (4 * j + 0);
        word |= (uint32_t)(v.y & 1) << (4 * j + 1);
        word |= (uint32_t)(v.z & 1) << (4 * j + 2);
        word |= (uint32_t)(v.w & 1) << (4 * j + 3);
    }
    out[w] = word;
}

// ---------------------------------------------------------------------------
// Scan: each block = 8 queries x 8192 keys. Threads 0..127 handle queries
// 0..3 (in registers), threads 128..255 handle queries 4..7. Keys staged in
// LDS 128 at a time, transposed+padded [w4][key] so both the staging write
// and the ds_read_b128 are at the bank-conflict floor. Packed best =
// (dist<<16)|key_idx minimized -> first-max argmax semantics of reference.
//
// __launch_bounds__(256, 2): VGPR cap 256 so q[4][8] (128 VGPRs) stays in
// registers. (256,3) capped at ~170 and spilled q to scratch -> 10.8 GB HBM.
__launch_bounds__(256, 2)
__global__ void scan_kernel(const uint32_t* __restrict__ qpack,
                            const uint32_t* __restrict__ kpack,
                            uint32_t* __restrict__ partials) {
    __shared__ uint4 lds[8 * LSTRIDE];  // [w4][key] padded, ~16.5 KB
    __shared__ uint32_t red[4][4];      // per-wave reduction scratch

    const int t     = threadIdx.x;
    const int ktile = blockIdx.x & 7;       // same ktile -> same XCD (L2 pin)
    const int qtile = blockIdx.x >> 3;
    const int g     = t >> 7;                // query group 0/1
    const int tk    = t & 127;               // key slot within chunk
    const int qbase = qtile * QB + g * QPT;

    const uint4* qp4 = reinterpret_cast<const uint4*>(qpack);
    const uint4* kp4 = reinterpret_cast<const uint4*>(kpack);

    // 4 queries resident in registers: 4 x 8 x uint4 = 128 VGPRs
    uint4 q[QPT][8];
#pragma unroll
    for (int i = 0; i < QPT; ++i)
#pragma unroll
        for (int j = 0; j < 8; ++j)
            q[i][j] = qp4[(size_t)(qbase + i) * 8 + j];

    uint32_t best[QPT] = {0xFFFFFFFFu, 0xFFFFFFFFu, 0xFFFFFFFFu, 0xFFFFFFFFu};

    const int k0 = ktile * KTILE;
    for (int c = 0; c < KTILE; c += CHUNK) {
        // ---- stage 128 keys (16 KB) into LDS, transposed+padded ----------
#pragma unroll
        for (int j = 0; j < 4; ++j) {
            int i = j * 256 + t;                       // linear uint4 index
            uint4 v = kp4[(size_t)(k0 + c) * 8 + i];   // coalesced
            lds[(i & 7) * LSTRIDE + (i >> 3)] = v;     // [w4][key]
        }
        __syncthreads();

        // ---- 1 key per thread vs 4 resident queries ----------------------
        uint32_t dist[QPT] = {0, 0, 0, 0};
#pragma unroll
        for (int w4 = 0; w4 < 8; ++w4) {
            uint4 kv = lds[w4 * LSTRIDE + tk];
#pragma unroll
            for (int i = 0; i < QPT; ++i) {
                dist[i] += __popc(kv.x ^ q[i][w4].x);
                dist[i] += __popc(kv.y ^ q[i][w4].y);
                dist[i] += __popc(kv.z ^ q[i][w4].z);
                dist[i] += __popc(kv.w ^ q[i][w4].w);
            }
        }
        uint32_t gk = (uint32_t)(k0 + c + tk);         // global key idx <= 65535
#pragma unroll
        for (int i = 0; i < QPT; ++i) {
            uint32_t packed = (dist[i] << 16) | gk;    // min => min dist, then min idx
            best[i] = min(best[i], packed);
        }
        __syncthreads();
    }

    // ---- reduce across the 128 threads of each group ----------------------
#pragma unroll
    for (int i = 0; i < QPT; ++i) {
        uint32_t b = best[i];
        for (int off = 32; off; off >>= 1)
            b = min(b, (uint32_t)__shfl_xor((int)b, off, 64));
        best[i] = b;
    }
    const int wave = t >> 6;
    if ((t & 63) == 0) {
#pragma unroll
        for (int i = 0; i < QPT; ++i) red[wave][i] = best[i];
    }
    __syncthreads();
    if (t < 8) {
        int g2 = t >> 2, i = t & 3;
        uint32_t v = min(red[g2 * 2][i], red[g2 * 2 + 1][i]);
        partials[(size_t)(qtile * QB + g2 * QPT + i) * 8 + ktile] = v;
    }
}

// ---------------------------------------------------------------------------
// Finalize: min over 8 ktile partials -> gather values row (1024 f32).
__global__ void finalize_kernel(const uint32_t* __restrict__ partials,
                                const float* __restrict__ values,
                                float* __restrict__ out) {
    const int q = blockIdx.x;
    const int t = threadIdx.x;
    uint32_t m = 0xFFFFFFFFu;
#pragma unroll
    for (int j = 0; j < 8; ++j) m = min(m, partials[q * 8 + j]);
    const int idx = (int)(m & 0xFFFFu);
    const float4* v4 = reinterpret_cast<const float4*>(values) + (size_t)idx * 256;
    float4* o4 = reinterpret_cast<float4*>(out) + (size_t)q * 256;
    o4[t] = v4[t];
}

// ---------------------------------------------------------------------------
extern "C" void kernel_launch(void* const* d_in, const int* in_sizes, int n_in,
                              void* d_out, int out_size, void* d_ws, size_t ws_size,
                              hipStream_t stream) {
    const int*   query  = (const int*)d_in[0];   // [2048, 1024] int32 0/1
    const int*   keys   = (const int*)d_in[1];   // [65536, 1024] int32 0/1
    const float* values = (const float*)d_in[2]; // [65536, 1024] f32
    float*       out    = (float*)d_out;         // [2048, 1024] f32

    char* ws = (char*)d_ws;
    uint32_t* qpack    = (uint32_t*)ws;                        // 256 KB
    uint32_t* kpack    = (uint32_t*)(ws + 262144);             // 8 MB
    uint32_t* partials = (uint32_t*)(ws + 262144 + 8388608);   // 64 KB

    pack_bits_kernel<<<BATCH * KEY_WORDS / 256, 256, 0, stream>>>(
        query, qpack, BATCH * KEY_WORDS);
    pack_bits_kernel<<<CAPACITY * KEY_WORDS / 256, 256, 0, stream>>>(
        keys, kpack, CAPACITY * KEY_WORDS);

    scan_kernel<<<(BATCH / QB) * (CAPACITY / KTILE), 256, 0, stream>>>(
        qpack, kpack, partials);

    finalize_kernel<<<BATCH, 256, 0, stream>>>(partials, values, out);
}

// Round 3
// 391.551 us; speedup vs baseline: 7.0408x; 1.6250x over previous
//
#include <hip/hip_runtime.h>
#include <stdint.h>

#define CAPACITY  65536
#define BATCH     2048
#define KEY_WORDS 32        // 1024 bits / 32
#define KTILE     8192      // keys per scan block (1 MB of packed keys = L2 tile)
#define QB        8         // queries per block
#define QPT       2         // queries per wave (4 waves/block, one query pair each)

// ---------------------------------------------------------------------------
// Pack 32 consecutive 0/1 int32s (as 8 int4s) into one u32. Same function for
// queries and keys so bit order matches.
__device__ __forceinline__ uint32_t pack_word(const int4* __restrict__ p) {
    uint32_t word = 0;
#pragma unroll
    for (int j = 0; j < 8; ++j) {
        int4 v = p[j];
        word |= (uint32_t)(v.x & 1) << (4 * j + 0);
        word |= (uint32_t)(v.y & 1) << (4 * j + 1);
        word |= (uint32_t)(v.z & 1) << (4 * j + 2);
        word |= (uint32_t)(v.w & 1) << (4 * j + 3);
    }
    return word;
}

// Row-major pack (used for queries): out[key][word].
__global__ void pack_bits_kernel(const int* __restrict__ in,
                                 uint32_t* __restrict__ out, int nwords) {
    int w = blockIdx.x * blockDim.x + threadIdx.x;
    if (w >= nwords) return;
    out[w] = pack_word(reinterpret_cast<const int4*>(in) + (size_t)w * 8);
}

// Transposed pack for keys: outT is u32[8 planes][CAPACITY][4], i.e. plane w4
// holds words 4*w4..4*w4+3 of every key. In the scan, lane tk loading plane
// w4 of key (k0+c+tk) is a fully coalesced 16B/lane uint4 load.
__global__ void pack_keys_t_kernel(const int* __restrict__ in,
                                   uint32_t* __restrict__ outT) {
    __shared__ uint32_t w_lds[8][32];
    const int t = threadIdx.x;          // 256 threads = 8 keys x 32 words
    const int b = blockIdx.x;           // 8 keys per block
    const int kl = t >> 5, w = t & 31;
    const int k = b * 8 + kl;
    w_lds[kl][w] = pack_word(reinterpret_cast<const int4*>(in)
                             + (size_t)k * 256 + w * 8);   // 128B/thread, coalesced
    __syncthreads();
    const int plane = t >> 5, idx = t & 31;    // 32 consecutive u32 per plane
    const int kl2 = idx >> 2, comp = idx & 3;
    outT[(size_t)plane * (CAPACITY * 4) + (size_t)(b * 8 + kl2) * 4 + comp]
        = w_lds[kl2][plane * 4 + comp];
}

// ---------------------------------------------------------------------------
// Scan: 8 queries x 8192 keys per block, 4 waves, each wave owns 2 queries
// (held in SGPRs via readfirstlane — query words are wave-uniform). Keys are
// read directly from the transposed global layout: coalesced, L2-resident
// (ktile == XCD id -> each XCD's L2 holds one 1 MB tile). No LDS, no barriers
// in the main loop -> compiler pipelines loads under the xor/popcount body.
// Packed best = (dist<<16)+key_idx minimized == first-max argmax semantics.
__launch_bounds__(256, 4)
__global__ void scan_kernel(const uint32_t* __restrict__ qpack,
                            const uint4* __restrict__ kq4,
                            uint32_t* __restrict__ partials) {
    const int t     = threadIdx.x;
    const int ktile = blockIdx.x & 7;       // == XCD id (L2 pin)
    const int qtile = blockIdx.x >> 3;
    const int g     = t >> 6;               // wave id = query-pair group
    const int tk    = t & 63;
    const int qbase = qtile * QB + g * QPT;

    // 2 queries resident in SGPRs (wave-uniform loads + readfirstlane)
    uint32_t qs[QPT][32];
    const uint4* qp4 = reinterpret_cast<const uint4*>(qpack);
#pragma unroll
    for (int i = 0; i < QPT; ++i)
#pragma unroll
        for (int j = 0; j < 8; ++j) {
            uint4 v = qp4[(size_t)(qbase + i) * 8 + j];
            qs[i][4 * j + 0] = __builtin_amdgcn_readfirstlane(v.x);
            qs[i][4 * j + 1] = __builtin_amdgcn_readfirstlane(v.y);
            qs[i][4 * j + 2] = __builtin_amdgcn_readfirstlane(v.z);
            qs[i][4 * j + 3] = __builtin_amdgcn_readfirstlane(v.w);
        }

    uint32_t best[QPT] = {0xFFFFFFFFu, 0xFFFFFFFFu};
    const int k0 = ktile * KTILE;

#pragma unroll 2
    for (int c = 0; c < KTILE; c += 64) {
        const int key = k0 + c + tk;
        uint4 kv[8];
#pragma unroll
        for (int w4 = 0; w4 < 8; ++w4)
            kv[w4] = kq4[(size_t)w4 * CAPACITY + key];   // coalesced 16B/lane

        uint32_t dist[QPT] = {0, 0};
#pragma unroll
        for (int w4 = 0; w4 < 8; ++w4)
#pragma unroll
            for (int i = 0; i < QPT; ++i) {
                dist[i] += __popc(kv[w4].x ^ qs[i][4 * w4 + 0]);
                dist[i] += __popc(kv[w4].y ^ qs[i][4 * w4 + 1]);
                dist[i] += __popc(kv[w4].z ^ qs[i][4 * w4 + 2]);
                dist[i] += __popc(kv[w4].w ^ qs[i][4 * w4 + 3]);
            }
#pragma unroll
        for (int i = 0; i < QPT; ++i)
            best[i] = min(best[i], (dist[i] << 16) + (uint32_t)key); // v_lshl_add
    }

    // wave-level reduce; each wave's queries are exclusive to it
#pragma unroll
    for (int i = 0; i < QPT; ++i) {
        uint32_t b = best[i];
        for (int off = 32; off; off >>= 1)
            b = min(b, (uint32_t)__shfl_xor((int)b, off, 64));
        if (tk == 0) partials[(size_t)(qbase + i) * 8 + ktile] = b;
    }
}

// ---------------------------------------------------------------------------
// Finalize: min over 8 ktile partials -> gather values row (1024 f32).
__global__ void finalize_kernel(const uint32_t* __restrict__ partials,
                                const float* __restrict__ values,
                                float* __restrict__ out) {
    const int q = blockIdx.x;
    const int t = threadIdx.x;
    uint32_t m = 0xFFFFFFFFu;
#pragma unroll
    for (int j = 0; j < 8; ++j) m = min(m, partials[q * 8 + j]);
    const int idx = (int)(m & 0xFFFFu);
    const float4* v4 = reinterpret_cast<const float4*>(values) + (size_t)idx * 256;
    float4* o4 = reinterpret_cast<float4*>(out) + (size_t)q * 256;
    o4[t] = v4[t];
}

// ---------------------------------------------------------------------------
extern "C" void kernel_launch(void* const* d_in, const int* in_sizes, int n_in,
                              void* d_out, int out_size, void* d_ws, size_t ws_size,
                              hipStream_t stream) {
    const int*   query  = (const int*)d_in[0];   // [2048, 1024] int32 0/1
    const int*   keys   = (const int*)d_in[1];   // [65536, 1024] int32 0/1
    const float* values = (const float*)d_in[2]; // [65536, 1024] f32
    float*       out    = (float*)d_out;         // [2048, 1024] f32

    char* ws = (char*)d_ws;
    uint32_t* qpack    = (uint32_t*)ws;                        // 256 KB
    uint32_t* kq4      = (uint32_t*)(ws + 262144);             // 8 MB transposed
    uint32_t* partials = (uint32_t*)(ws + 262144 + 8388608);   // 64 KB

    pack_bits_kernel<<<BATCH * KEY_WORDS / 256, 256, 0, stream>>>(
        query, qpack, BATCH * KEY_WORDS);
    pack_keys_t_kernel<<<CAPACITY / 8, 256, 0, stream>>>(keys, kq4);

    scan_kernel<<<(BATCH / QB) * (CAPACITY / KTILE), 256, 0, stream>>>(
        qpack, reinterpret_cast<const uint4*>(kq4), partials);

    finalize_kernel<<<BATCH, 256, 0, stream>>>(partials, values, out);
}